// Round 5
// baseline (272.104 us; speedup 1.0000x reference)
//
#include <hip/hip_runtime.h>

// SparseMaxPool, single-visit full-line NONTEMPORAL stores (R4 + nt).
// Theory: harness poison-fill leaves dirty lines in L2/MALL over the output
// range; cached stores displace them -> ~2x HBM write traffic. nt stores
// stream past the cache, avoiding poison-eviction bandwidth.
// Valid offsets o=c-r: 0..15 (any r), odd 17..31 (r even), o%4==3 in 35..63
// (r%4==0), o%8==7 in 71..127 (r%8==0).
// Doubling table in LDS: level-k base lb(k)=129k-(2^k-1), len 129-2^k, 777 used.

#define NN 128
#define SLICE_ELEMS (NN * NN)

typedef float f32x4 __attribute__((ext_vector_type(4)));

__device__ __forceinline__ bool ok_elem(int o, bool u1, bool u3, bool u7) {
    // class check: o<16 always ok; 16..31 needs u1; 32..63 u3; >=64 u7
    bool cls = (o < 16) ? true : (o < 32) ? u1 : (o < 64) ? u3 : u7;
    return (o >= 0) && cls;
}

__global__ __launch_bounds__(256) void sparse_maxpool_kernel(
        const float* __restrict__ x, float* __restrict__ out) {
    __shared__ float buf[1040];        // 777 table + pad (OOB-safe reads)
    const int tid = threadIdx.x;
    const int slice = blockIdx.x;      // b*256 + d, 4096 total

    // Level 0 = x slice; zero the pad so masked lanes read benign values.
    if (tid < NN) buf[tid] = x[(size_t)slice * NN + tid];
    for (int i = tid; i < 1040 - 777; i += 256) buf[777 + i] = 0.0f;
    __syncthreads();

    // Levels 1..7: P[k][i] = max(P[k-1][i], P[k-1][i + 2^{k-1}])
    int base_prev = 0, base_cur = NN;
    #pragma unroll
    for (int k = 1; k <= 7; ++k) {
        int half = 1 << (k - 1);
        int len = (NN + 1) - (1 << k);
        if (tid < len)
            buf[base_cur + tid] = fmaxf(buf[base_prev + tid], buf[base_prev + tid + half]);
        __syncthreads();
        base_prev = base_cur;
        base_cur += len;
    }

    const int c0 = (tid & 31) << 2;    // fixed columns per thread
    const int q  = tid >> 5;           // r = 8*it + q
    // Hoisted residue-class validity: o_j & 7 == (c0 + j - q) & 7, r & 7 == q & 7
    const bool qe1 = (q & 1) == 0, qe3 = (q & 3) == 0, qe7 = (q & 7) == 0;
    bool u1[4], u3[4], u7[4];
    #pragma unroll
    for (int j = 0; j < 4; ++j) {
        int rho = (c0 + j - q) & 7;
        u1[j] = ((rho & 1) == 1) && qe1;
        u3[j] = ((rho & 3) == 3) && qe3;
        u7[j] = (rho == 7)       && qe7;
    }

    f32x4* __restrict__ o4 = reinterpret_cast<f32x4*>(out + (size_t)slice * SLICE_ELEMS);

    #pragma unroll 4
    for (int it = 0; it < 16; ++it) {
        const int r  = (it << 3) + q;
        const int o0 = c0 - r;
        const int w0 = o0 + 1;
        const int wc = w0 < 1 ? 1 : w0;     // 1..125
        const int k0 = 31 - __clz(wc);      // 0..6
        const int p  = 1 << k0;
        const int lb0 = 129 * k0 - p + 1;   // level k0 base
        const int aA = lb0 + r;             // P_k0[r]
        const int aV = lb0 + c0 + 1 - p;    // run of level-k0 second operands (>=0)
        const int aB = lb0 + 129 - p + r;   // P_{k0+1}[r..r+2]
        const int s  = 2 * p - w0 + 1;      // first j on level k0+1 (s >= 2)

        const float A0  = buf[aA];
        const float VA0 = buf[aV],     VA1 = buf[aV + 1];
        const float VA2 = buf[aV + 2], VA3 = buf[aV + 3];
        const float VB0 = buf[aB],     VB1 = buf[aB + 1], VB2 = buf[aB + 2];

        const float e0 = fmaxf(A0, VA0);
        const float e1 = fmaxf(A0, VA1);
        const float e2 = (s == 2) ? fmaxf(VB0, VB1) : fmaxf(A0, VA2);
        const float e3 = (s <= 3) ? fmaxf(VB0, (s == 2) ? VB2 : VB1)
                                  : fmaxf(A0, VA3);

        f32x4 v;
        v.x = ok_elem(o0,     u1[0], u3[0], u7[0]) ? e0 : 0.0f;
        v.y = ok_elem(o0 + 1, u1[1], u3[1], u7[1]) ? e1 : 0.0f;
        v.z = ok_elem(o0 + 2, u1[2], u3[2], u7[2]) ? e2 : 0.0f;
        v.w = ok_elem(o0 + 3, u1[3], u3[3], u7[3]) ? e3 : 0.0f;

        __builtin_nontemporal_store(v, &o4[(it << 8) + tid]);
    }
}

extern "C" void kernel_launch(void* const* d_in, const int* in_sizes, int n_in,
                              void* d_out, int out_size, void* d_ws, size_t ws_size,
                              hipStream_t stream) {
    const float* x = (const float*)d_in[0];
    float* out = (float*)d_out;
    const int slices = in_sizes[0] / NN;   // 16*256 = 4096
    sparse_maxpool_kernel<<<dim3(slices), dim3(256), 0, stream>>>(x, out);
}